// Round 10
// baseline (36.802 us; speedup 1.0000x reference)
//
#include <hip/hip_runtime.h>
#include <math.h>

// Problem constants: B=2, C=16, D=64, H=128, W=128, K=4
#define SPATIAL (64 * 128 * 128)   // 2^20 voxels per sample
#define NCLS 16
#define NB 2
#define WIN 512                    // voxels per block window
#define NBLK 4096                  // 4096 * 512 = 2*SPATIAL exactly
#define TPB 256

// Ledger: ticket-fused finalize = +120us fixed (R2/R5) -> 2 kernels.
// float4[16] front-load -> scratch spill (R2). 8vox/thr halves occupancy (R6).
// chunk rotation null (R7). nt loads -7% (R9). This round: PLANAR -- each wave
// streams linearly within one plane (copy-like), cross-class combine via LDS.
// Tests whether 16 interleaved 4MiB-stride streams/wave are the ~4.8TB/s cap.

typedef float  f32x4 __attribute__((ext_vector_type(4)));
typedef int    i32x4 __attribute__((ext_vector_type(4)));

__device__ __forceinline__ f32x4 ntload4(const float* p) {
    return __builtin_nontemporal_load(reinterpret_cast<const f32x4*>(p));
}
__device__ __forceinline__ i32x4 ntload4i(const int* p) {
    return __builtin_nontemporal_load(reinterpret_cast<const i32x4*>(p));
}

__global__ __launch_bounds__(TPB) void bce_planar(
    const float* __restrict__ probs,    // [B, C, SPATIAL]
    const int*   __restrict__ target,   // [B, SPATIAL]
    const int*   __restrict__ ann,      // [B, 4]
    float*       __restrict__ partials) // [5][NBLK]
{
    const int wbg  = blockIdx.x * WIN;          // global voxel base of window
    const int b    = wbg >> 20;                 // sample (2^20 % WIN == 0)
    const int s    = wbg & (SPATIAL - 1);
    const int wave = threadIdx.x >> 6;
    const int lane = threadIdx.x & 63;

    // Unannotated-class bitmask (class 0 never annotated as fg).
    unsigned am = 0;
#pragma unroll
    for (int k = 0; k < 4; ++k) {
        const int c = ann[b * 4 + k];
        if (c > 0) am |= (1u << c);
    }
    const unsigned m = ~am & 0xFFFFu;

    // Lane's two voxel quartets within the window: A at 4*lane, B at 256+4*lane.
    const int la = 4 * lane;
    const int lb = 256 + 4 * lane;

    // Targets for the loader phase (per-lane, 16B coalesced).
    const i32x4 tA = ntload4i(target + wbg + la);
    const i32x4 tB = ntload4i(target + wbg + lb);
    const int ta[4] = {tA.x, tA.y, tA.z, tA.w};
    const int tb[4] = {tB.x, tB.y, tB.z, tB.w};

    // Wave w streams planes 4w..4w+3, each 2KB window read linearly.
    const float* pw = probs + (size_t)b * NCLS * SPATIAL + (size_t)(wave * 4) * SPATIAL + s;

    float entA[4] = {0.f, 0.f, 0.f, 0.f}, pfA[4] = {0.f, 0.f, 0.f, 0.f};
    float entB[4] = {0.f, 0.f, 0.f, 0.f}, pfB[4] = {0.f, 0.f, 0.f, 0.f};

    f32x4 bufA[2], bufB[2];
    bufA[0] = ntload4(pw + la);
    bufB[0] = ntload4(pw + lb);

#pragma unroll
    for (int k = 0; k < 4; ++k) {
        const int cur = k & 1, nxt = cur ^ 1;
        if (k < 3) {
            bufA[nxt] = ntload4(pw + (size_t)(k + 1) * SPATIAL + la);
            bufB[nxt] = ntload4(pw + (size_t)(k + 1) * SPATIAL + lb);
        }
        const int cls = wave * 4 + k;               // wave-uniform
        const bool un = (m >> cls) & 1u;
        const float pA[4] = {bufA[cur].x, bufA[cur].y, bufA[cur].z, bufA[cur].w};
        const float pB[4] = {bufB[cur].x, bufB[cur].y, bufB[cur].z, bufB[cur].w};
#pragma unroll
        for (int q = 0; q < 4; ++q) {
            // entropy partial: p * log2(clamp(p))
            const float pcA = fminf(fmaxf(pA[q], 1e-6f), 0.999999f);
            entA[q] = fmaf(pA[q], __log2f(pcA), entA[q]);
            const float pcB = fminf(fmaxf(pB[q], 1e-6f), 0.999999f);
            entB[q] = fmaf(pB[q], __log2f(pcB), entB[q]);
            // selected-p partial: fg -> p at target class; bg -> sum of unannot p
            pfA[q] += (ta[q] > 0) ? ((cls == ta[q]) ? pA[q] : 0.f)
                                  : (un ? pA[q] : 0.f);
            pfB[q] += (tb[q] > 0) ? ((cls == tb[q]) ? pB[q] : 0.f)
                                  : (un ? pB[q] : 0.f);
        }
    }

    // Per-wave partials -> LDS (linear, conflict-free b128 stores).
    __shared__ float lent[4][WIN];
    __shared__ float lpf [4][WIN];
    *reinterpret_cast<f32x4*>(&lent[wave][la]) = f32x4{entA[0], entA[1], entA[2], entA[3]};
    *reinterpret_cast<f32x4*>(&lent[wave][lb]) = f32x4{entB[0], entB[1], entB[2], entB[3]};
    *reinterpret_cast<f32x4*>(&lpf [wave][la]) = f32x4{pfA[0], pfA[1], pfA[2], pfA[3]};
    *reinterpret_cast<f32x4*>(&lpf [wave][lb]) = f32x4{pfB[0], pfB[1], pfB[2], pfB[3]};
    __syncthreads();

    // Combine: each thread finalizes 2 voxels (tid, tid+256).
    float ce_sum = 0.f, ent_b = 0.f, cnt_b = 0.f;
#pragma unroll
    for (int h = 0; h < 2; ++h) {
        const int v = threadIdx.x + h * 256;
        const float ENT = ((lent[0][v] + lent[1][v]) + (lent[2][v] + lent[3][v]));
        const float p   = ((lpf[0][v] + lpf[1][v]) + (lpf[2][v] + lpf[3][v]));
        const int   t   = target[wbg + v];          // L1/L2-hot reload
        const float pc  = fminf(fmaxf(p, 1e-6f), 0.999999f);
        const float om  = 1.f - p;                  // focal uses UNclamped p
        ce_sum += om * om * __log2f(pc);
        ent_b  += ENT;
        cnt_b  += (t != 0) ? 1.f : 0.f;
    }

    float vals[5];
    vals[0] = ce_sum;
    vals[1] = (b == 0) ? ent_b : 0.f;
    vals[2] = (b == 1) ? ent_b : 0.f;
    vals[3] = (b == 0) ? cnt_b : 0.f;
    vals[4] = (b == 1) ? cnt_b : 0.f;

    __shared__ float red[5][TPB / 64];
#pragma unroll
    for (int qq = 0; qq < 5; ++qq) {
        float x = vals[qq];
#pragma unroll
        for (int off = 32; off > 0; off >>= 1)
            x += __shfl_down(x, off, 64);
        if (lane == 0) red[qq][wave] = x;
    }
    __syncthreads();
    if (threadIdx.x == 0) {
#pragma unroll
        for (int qq = 0; qq < 5; ++qq) {
            float x = 0.f;
#pragma unroll
            for (int w = 0; w < TPB / 64; ++w) x += red[qq][w];
            partials[qq * NBLK + blockIdx.x] = x;
        }
    }
}

// ---------------- finalize: single wave, no barriers, float4 reads ----------------
__global__ __launch_bounds__(64) void bce_final(
    const float* __restrict__ partials, float* __restrict__ out)
{
    const int lane = threadIdx.x;   // 64 threads = 1 wave
    float acc[5] = {0.f, 0.f, 0.f, 0.f, 0.f};
#pragma unroll
    for (int qq = 0; qq < 5; ++qq) {
        const float4* src = reinterpret_cast<const float4*>(partials + qq * NBLK);
#pragma unroll
        for (int i = 0; i < 16; ++i) {              // 4096 = 64 lanes * 16 float4
            const float4 x = src[i * 64 + lane];
            acc[qq] += (x.x + x.y) + (x.z + x.w);
        }
    }
#pragma unroll
    for (int qq = 0; qq < 5; ++qq) {
#pragma unroll
        for (int off = 32; off > 0; off >>= 1)
            acc[qq] += __shfl_down(acc[qq], off, 64);
    }
    if (lane == 0) {
        const float ce = acc[0], e0 = acc[1], e1 = acc[2], c0 = acc[3], c1 = acc[4];
        const float LN2  = 0.69314718055994530942f;
        const float invS = 1.f / (float)SPATIAL;
        const float ent0 = e0 * LN2 * invS;
        const float ent1 = e1 * LN2 * invS;
        const float m0   = (c0 == 0.f) ? 3.f : 1.f;   // all_bg -> MULT_UNLABELED
        const float m1   = (c1 == 0.f) ? 3.f : 1.f;
        out[0] = -(ce * LN2) / (float)(NB * SPATIAL);
        out[1] = -(m0 * ent0 + m1 * ent1) * 0.5f;
    }
}

extern "C" void kernel_launch(void* const* d_in, const int* in_sizes, int n_in,
                              void* d_out, int out_size, void* d_ws, size_t ws_size,
                              hipStream_t stream) {
    const float* probs  = (const float*)d_in[0];
    const int*   target = (const int*)d_in[1];
    const int*   ann    = (const int*)d_in[2];
    float*       out    = (float*)d_out;
    float*       partials = (float*)d_ws;   // 5 * NBLK * 4 B = 80 KiB

    bce_planar<<<NBLK, TPB, 0, stream>>>(probs, target, ann, partials);
    bce_final<<<1, 64, 0, stream>>>(partials, out);
}